// Round 7
// baseline (635.670 us; speedup 1.0000x reference)
//
#include <hip/hip_runtime.h>
#include <math.h>

#define Hc   128
#define Bc   512
#define Tc   64
#define NXc  518
#define NCELL (518*518)
#define NEV  (Bc*Tc)            // 32768 events
#define SWc  2

// ---------------- precompute kernels ----------------

__global__ void k_build(const float* __restrict__ feat, int* __restrict__ head,
                        int* __restrict__ nxt, int* __restrict__ cellxy) {
    int gid = blockIdx.x * 256 + threadIdx.x;
    if (gid >= NEV) return;
    int b = gid >> 6, t = gid & 63;
    int base = (b * Tc + t) * 4;
    int gx = (int)feat[base + 2] + SWc;
    int gy = (int)feat[base + 3] + SWc;
    gx = min(max(gx, 0), NXc - 1);
    gy = min(max(gy, 0), NXc - 1);
    int cell = gx * NXc + gy;
    int e = t * Bc + b;
    cellxy[e] = (gx << 16) | gy;
    int old = atomicExch(&head[cell], e);
    nxt[e] = old;
}

__global__ void k_resolve(const int* __restrict__ head, const int* __restrict__ nxt,
                          const int* __restrict__ cellxy, int* __restrict__ dep) {
    int gid = blockIdx.x * 256 + threadIdx.x;
    if (gid >= NEV * 25) return;
    int r = gid / 25, k = gid - r * 25;
    int t = r & 63, b = r >> 6;
    int e0 = t * Bc + b;
    int xy = cellxy[e0];
    int gx = xy >> 16, gy = xy & 0xffff;
    int cx = gx + (k / 5) - SWc, cy = gy + (k % 5) - SWc;
    cx = min(max(cx, 0), NXc - 1);
    cy = min(max(cy, 0), NXc - 1);
    int cell = cx * NXc + cy;
    int best = -1;
    for (int e = head[cell]; e >= 0; e = nxt[e])
        if ((e >> 9) < t && e > best) best = e;
    dep[r * 25 + k] = best;
}

// ---------------- fast math ----------------

#define LOG2E 1.4426950408889634f
__device__ __forceinline__ float fexp(float x)  { return __builtin_amdgcn_exp2f(x * LOG2E); }
__device__ __forceinline__ float fsig(float x)  { return __builtin_amdgcn_rcpf(1.f + fexp(-x)); }
__device__ __forceinline__ float ftanh(float x) { return 1.f - 2.f * __builtin_amdgcn_rcpf(1.f + fexp(2.f * x)); }

// Raw barrier: waits LDS only (lgkmcnt(0)); global loads stay IN FLIGHT across
// phases. asm memory clobbers stop IR-level store-forwarding across the barrier.
__device__ __forceinline__ void barlds() {
    asm volatile("" ::: "memory");
    __builtin_amdgcn_s_waitcnt(0xC07F);   // vmcnt=63, expcnt=7, lgkmcnt=0
    __builtin_amdgcn_s_barrier();
    asm volatile("" ::: "memory");
}

// ---------------- main persistent dataflow kernel ----------------

#define WSTRIDE 257
#define L_WOUT  (128 * WSTRIDE)
constexpr int LDS_FLOATS = L_WOUT + 256 + 1024 + 256 + 256 + 256 + 256 + 256 + 64 + 2048 + 16 + 128 + 256 + 64;
constexpr int LDS_BYTES  = LDS_FLOATS * 4;   // ~152 KB <= 160 KiB

__global__ void
__attribute__((amdgpu_flat_work_group_size(1024, 1024)))
__attribute__((amdgpu_waves_per_eu(4, 4)))
step_main(const float* __restrict__ feat, const float* __restrict__ Wih,
          const float* __restrict__ bih,  const float* __restrict__ Whh,
          const float* __restrict__ bhh,  const float* __restrict__ Wout,
          const float* __restrict__ bout, const int*   __restrict__ seq,
          const int*   __restrict__ dep,  float* __restrict__ vbuf,
          unsigned*    __restrict__ flags, float* __restrict__ dout) {
    extern __shared__ float lds[];
    float* WoutL = lds;                 // 128*257
    float* hid   = WoutL + L_WOUT;      // 2*128
    float* g     = hid   + 256;         // 2*512 gate pre-acts; reused as cat[2][256]
    float* gin   = g     + 1024;        // 2*128
    float* qv    = gin   + 256;
    float* ug    = qv    + 256;
    float* sg    = ug    + 256;
    float* ctr   = sg    + 256;
    float* scor  = ctr   + 256;         // 2*32
    float* pmix  = scor  + 64;          // 16 rows * 128
    float* fxy   = pmix  + 2048;        // 2 parities * 8
    float* boutL = fxy   + 16;          // 128
    float* updL  = boutL + 128;         // 2*128 deferred vbuf payload
    int*   depv  = (int*)(updL + 256);  // 2*25 (+pad), deps for step t+1

    const int tid  = threadIdx.x;       // 0..1023
    const int blk  = blockIdx.x;
    const int lane = tid & 63;
    const int w    = tid >> 6;          // wave 0..15
    const int wj   = w >> 3;            // chain of this wave
    const int ww   = w & 7;             // wave-within-chain (8 per chain)

    // ---- persistent register weights: HALF a W_hh row per thread (64 VGPRs) ----
    const int o    = tid >> 1;
    const int half = tid & 1;
    float4 wr[16];                      // statically indexed only (rule #20)
    {
        const float4* wp = (const float4*)(Whh + (size_t)o * Hc + half * 64);
        #pragma unroll
        for (int i = 0; i < 16; ++i) wr[i] = wp[i];
    }
    const float bihr = bih[o], bhhr = bhh[o];
    const float wih0 = Wih[o * 2 + 0], wih1 = Wih[o * 2 + 1];
    const int chunk = o >> 7;

    // stage W_out (stride-257) + b_out into LDS
    for (int i = tid; i < 128 * 256; i += 1024)
        WoutL[(i >> 8) * WSTRIDE + (i & 255)] = Wout[i];
    if (tid < 128) boutL[tid] = bout[tid];
    if (tid < 256) hid[tid] = 0.f;
    if (tid < 8) { int j = tid >> 2, c = tid & 3;
                   fxy[tid] = feat[((size_t)(blk * 2 + j) * Tc + 0) * 4 + c]; }
    const int s0 = max(seq[blk * 2 + 0], 1) - 1;
    const int s1 = max(seq[blk * 2 + 1], 1) - 1;
    __syncthreads();

    const float NEG_INF = -__builtin_inff();

    // per-wave dep state (deps at t=0 are all -1 by construction)
    int ev[4]; bool pend[4]; float2 valk[4];
    #pragma unroll
    for (int kk = 0; kk < 4; ++kk) { ev[kk] = -1; pend[kk] = false; valk[kk] = make_float2(0.f, 0.f); }

    for (int t = 0; t < Tc; ++t) {
        const float* fx = fxy + (t & 1) * 8;

        // ======== A: deferred vbuf store (t-1) + gh GEMV + dep/fxy prefetch + flag release ========
        if (t > 0 && w < 2) {           // wave w owns chain w's publish
            float2 u = *(const float2*)&updL[w * 128 + 2 * lane];
            unsigned long long raw; __builtin_memcpy(&raw, &u, 8);
            __hip_atomic_store((unsigned long long*)(vbuf + ((size_t)((t - 1) * Bc + blk * 2 + w)) * Hc + 2 * lane),
                               raw, __ATOMIC_RELAXED, __HIP_MEMORY_SCOPE_AGENT);
        }
        float acc0j, acc1j;
        {
            const float4* hp0 = (const float4*)(hid + half * 64);
            const float4* hp1 = (const float4*)(hid + 128 + half * 64);
            float a0 = 0.f, a1 = 0.f, a2 = 0.f, a3 = 0.f;
            float b0 = 0.f, b1 = 0.f, b2 = 0.f, b3 = 0.f;
            #pragma unroll
            for (int i = 0; i < 16; ++i) {
                float4 w4 = wr[i];
                float4 h0 = hp0[i], h1 = hp1[i];
                a0 = fmaf(w4.x, h0.x, a0); a1 = fmaf(w4.y, h0.y, a1);
                a2 = fmaf(w4.z, h0.z, a2); a3 = fmaf(w4.w, h0.w, a3);
                b0 = fmaf(w4.x, h1.x, b0); b1 = fmaf(w4.y, h1.y, b1);
                b2 = fmaf(w4.z, h1.z, b2); b3 = fmaf(w4.w, h1.w, b3);
            }
            acc0j = (a0 + a1) + (a2 + a3);
            acc1j = (b0 + b1) + (b2 + b3);
        }
        acc0j += __shfl_xor(acc0j, 1, 64);
        acc1j += __shfl_xor(acc1j, 1, 64);
        if (half == 0) {
            float gi0 = fmaf(wih0, fx[0], wih1 * fx[1]);
            float gi1 = fmaf(wih0, fx[4], wih1 * fx[5]);
            g[o]       = acc0j + bhhr + ((chunk == 2) ? 0.f : (gi0 + bihr));
            g[512 + o] = acc1j + bhhr + ((chunk == 2) ? 0.f : (gi1 + bihr));
            if (chunk == 2) { gin[o & 127] = gi0 + bihr; gin[128 + (o & 127)] = gi1 + bihr; }
        }
        if (tid >= 512 && tid < 562 && t + 1 < Tc) {   // deps for t+1 (waves 8)
            int idx = tid - 512;
            int j = (idx >= 25), k = idx - j * 25;
            depv[idx] = dep[(((size_t)(blk * 2 + j)) * Tc + (t + 1)) * 25 + k];
        }
        if (tid >= 960 && tid < 968 && t + 1 < Tc) {   // fxy for t+1 (wave 15)
            int idx = tid - 960, j = idx >> 2, c = idx & 3;
            fxy[((t + 1) & 1) * 8 + idx] =
                feat[((size_t)(blk * 2 + j) * Tc + (t + 1)) * 4 + c];
        }
        if (t > 0 && w < 2) {
            asm volatile("" ::: "memory");
            __builtin_amdgcn_s_waitcnt(0x0F70);        // vmcnt(0): vbuf stores done
            if (lane == 0)
                __hip_atomic_store(&flags[(t - 1) * Bc + blk * 2 + w], 1u,
                                   __ATOMIC_RELAXED, __HIP_MEMORY_SCOPE_AGENT);
        }
        barlds();

        // ======== B: gates + spin on the (rare) fresh deps ========
        if (tid < 256) {
            int j = tid >> 7, h = tid & 127;
            float gr = g[j * 512 + h],       gu = g[j * 512 + 128 + h];
            float gn = g[j * 512 + 256 + h], gs = g[j * 512 + 384 + h];
            float rr = fsig(gr), uu = fsig(gu), ss = fsig(gs);
            float nn = ftanh(gin[j * 128 + h] + rr * gn);
            qv[j * 128 + h] = nn; ug[j * 128 + h] = uu; sg[j * 128 + h] = ss;
            ctr[j * 128 + h] = 0.f;
        }
        {
            bool nl0 = pend[0], nl1 = pend[1], nl2 = pend[2], nl3 = pend[3];
            while (__any(pend[0] | pend[1] | pend[2] | pend[3])) {
                #pragma unroll
                for (int kk = 0; kk < 4; ++kk)
                    if (pend[kk] && __hip_atomic_load(&flags[ev[kk]], __ATOMIC_RELAXED,
                                                      __HIP_MEMORY_SCOPE_AGENT) != 0u)
                        pend[kk] = false;
                if (__any(pend[0] | pend[1] | pend[2] | pend[3]))
                    __builtin_amdgcn_s_sleep(1);
            }
            asm volatile("" ::: "memory");   // vbuf loads below stay after the spin
            if (nl0) valk[0] = *(const float2*)(vbuf + (size_t)ev[0] * Hc + 2 * lane);
            if (nl1) valk[1] = *(const float2*)(vbuf + (size_t)ev[1] * Hc + 2 * lane);
            if (nl2) valk[2] = *(const float2*)(vbuf + (size_t)ev[2] * Hc + 2 * lane);
            if (nl3) valk[3] = *(const float2*)(vbuf + (size_t)ev[3] * Hc + 2 * lane);
        }
        barlds();

        // ======== C: scores from prefetched valk ========
        {
            const float q0 = qv[wj * 128 + 2 * lane];
            const float q1 = qv[wj * 128 + 2 * lane + 1];
            #pragma unroll
            for (int kk = 0; kk < 4; ++kk) {
                int k = ww + 8 * kk;
                if (k < 25) {
                    float sc;
                    if (ev[kk] >= 0) {
                        float2 v = valk[kk];
                        float d = fmaf(v.x, q0, v.y * q1);
                        #pragma unroll
                        for (int m = 1; m < 64; m <<= 1) d += __shfl_xor(d, m, 64);
                        sc = (d == 0.f) ? NEG_INF : d;
                        if (k == 12) { ctr[wj * 128 + 2 * lane]     = v.x;
                                       ctr[wj * 128 + 2 * lane + 1] = v.y; }
                    } else sc = NEG_INF;
                    if (lane == 0) scor[wj * 32 + k] = sc;
                }
            }
        }
        barlds();

        // ======== D: per-wave softmax + mix partials ========
        {
            int k2 = lane & 31;
            float v = (k2 < 25) ? scor[wj * 32 + k2] : NEG_INF;
            float m = v;
            #pragma unroll
            for (int mm = 1; mm < 32; mm <<= 1) m = fmaxf(m, __shfl_xor(m, mm, 64));
            float a = 0.f;
            if (m != NEG_INF) {
                float p = (v == NEG_INF) ? 0.f : fexp(v - m);
                float s = p;
                #pragma unroll
                for (int mm = 1; mm < 32; mm <<= 1) s += __shfl_xor(s, mm, 64);
                a = p / s;
            }
            float pm0 = 0.f, pm1 = 0.f;
            #pragma unroll
            for (int kk = 0; kk < 4; ++kk) {
                int k = ww + 8 * kk;
                if (k < 25 && ev[kk] >= 0) {
                    float ak = __shfl(a, k, 64);
                    pm0 = fmaf(ak, valk[kk].x, pm0);
                    pm1 = fmaf(ak, valk[kk].y, pm1);
                }
            }
            *(float2*)&pmix[(wj * 8 + ww) * 128 + 2 * lane] = make_float2(pm0, pm1);
        }
        barlds();

        // ======== E1: cat build + EARLY CHECK/PREFETCH for t+1 ========
        if (tid < 256) {
            int j = tid >> 7, h = tid & 127;
            float mix = 0.f;
            #pragma unroll
            for (int p = 0; p < 8; ++p) mix += pmix[(j * 8 + p) * 128 + h];
            g[j * 512 + h] = mix;
            g[j * 512 + 128 + h] = qv[j * 128 + h];
        }
        {
            bool okv[4];
            #pragma unroll
            for (int kk = 0; kk < 4; ++kk) {
                int k = ww + 8 * kk;
                int e = -1;
                if (t + 1 < Tc && k < 25) e = depv[wj * 25 + k];
                ev[kk] = e; okv[kk] = false; pend[kk] = false;
                if (e >= 0) {
                    okv[kk] = (__hip_atomic_load(&flags[e], __ATOMIC_RELAXED,
                                                 __HIP_MEMORY_SCOPE_AGENT) != 0u);
                    pend[kk] = !okv[kk];
                }
            }
            asm volatile("" ::: "memory");   // value loads strictly after flag checks
            #pragma unroll
            for (int kk = 0; kk < 4; ++kk) {
                valk[kk] = make_float2(0.f, 0.f);
                if (okv[kk])
                    valk[kk] = *(const float2*)(vbuf + (size_t)ev[kk] * Hc + 2 * lane);
            }
        }
        barlds();

        // ======== E2: W_out partial dots (8-way col split) ========
        {
            int oo = tid & 127, rep = tid >> 7;
            const float* wrow = WoutL + oo * WSTRIDE + rep * 32;
            const float* c0   = g + rep * 32;
            const float* c1   = g + 512 + rep * 32;
            float acc0 = 0.f, acc1 = 0.f;
            #pragma unroll
            for (int i = 0; i < 32; ++i) {
                float wv = wrow[i];
                acc0 = fmaf(wv, c0[i], acc0);
                acc1 = fmaf(wv, c1[i], acc1);
            }
            pmix[rep * 128 + oo]       = acc0;
            pmix[(8 + rep) * 128 + oo] = acc1;
        }
        barlds();

        // ======== E3: epilogue -> hid + updL (vbuf store deferred to A of t+1) ========
        if (tid < 256) {
            int j = tid >> 7, h = tid & 127;
            float tot = boutL[h];
            #pragma unroll
            for (int p = 0; p < 8; ++p) tot += pmix[(j * 8 + p) * 128 + h];
            float at = ftanh(tot);
            float n  = qv[j * 128 + h], uu = ug[j * 128 + h];
            float ss = sg[j * 128 + h], hv = hid[j * 128 + h];
            float curr = fmaf(ss, at, n);
            float outv = curr + uu * (hv - curr);
            hid[j * 128 + h] = outv;
            if (t < Tc - 1)   // t=63 values are never consumed
                updL[tid] = fmaf(ss, ctr[j * 128 + h], (1.f - ss) * outv);
            int sj = (j == 0) ? s0 : s1;
            if (sj == t) dout[(size_t)(blk * 2 + j) * Hc + h] = outv;
        }
        barlds();
    }
}

// ---------------- host launch ----------------

extern "C" void kernel_launch(void* const* d_in, const int* in_sizes, int n_in,
                              void* d_out, int out_size, void* d_ws, size_t ws_size,
                              hipStream_t stream) {
    const float* feat = (const float*)d_in[0];
    const float* Wih  = (const float*)d_in[1];
    const float* bih  = (const float*)d_in[2];
    const float* Whh  = (const float*)d_in[3];
    const float* bhh  = (const float*)d_in[4];
    const float* Wout = (const float*)d_in[5];
    const float* bout = (const float*)d_in[6];
    const int*   seq  = (const int*)d_in[7];

    char* ws = (char*)d_ws;
    size_t off = 0;
    auto carve = [&](size_t bytes) { char* p = ws + off; off += (bytes + 511) & ~(size_t)511; return p; };
    float*    vbuf   = (float*)   carve((size_t)NEV * Hc * 4);
    int*      head   = (int*)     carve((size_t)NCELL * 4);
    int*      nxt    = (int*)     carve((size_t)NEV * 4);
    int*      cellxy = (int*)     carve((size_t)NEV * 4);
    int*      dep    = (int*)     carve((size_t)NEV * 25 * 4);
    unsigned* flags  = (unsigned*)carve((size_t)NEV * 4);

    hipMemsetAsync(head, 0xFF, (size_t)NCELL * 4, stream);
    hipMemsetAsync(flags, 0, (size_t)NEV * 4, stream);

    k_build<<<(NEV + 255) / 256, 256, 0, stream>>>(feat, head, nxt, cellxy);
    k_resolve<<<(NEV * 25 + 255) / 256, 256, 0, stream>>>(head, nxt, cellxy, dep);

    hipFuncSetAttribute((const void*)step_main,
                        hipFuncAttributeMaxDynamicSharedMemorySize, LDS_BYTES);
    step_main<<<256, 1024, LDS_BYTES, stream>>>(feat, Wih, bih, Whh, bhh, Wout, bout,
                                                seq, dep, vbuf, flags, (float*)d_out);
}